// Round 1
// baseline (1409.662 us; speedup 1.0000x reference)
//
#include <hip/hip_runtime.h>

#define NCLS 80
#define MAXB 20
#define N0 27648     // 96*96*3
#define N1 110592    // 192*192*3
#define NTOT (N0 + N1)
#define CAP 8192     // per-class candidate capacity in workspace
#define LCAP 7680    // per-class candidate capacity in LDS (60KB of score+idx)

__device__ __forceinline__ float sigf(float x) {
    return 1.0f / (1.0f + expf(-x));
}

__global__ __launch_bounds__(128) void init_counts(int* counts) {
    int t = threadIdx.x;
    if (t < NCLS) counts[t] = 0;
}

// One thread per anchor. Decodes box, conf-gates the 80-class loop, pushes
// (score, global_idx) candidates into per-class lists.
__global__ __launch_bounds__(256) void decode_kernel(
    const float* __restrict__ feats, float4* __restrict__ boxes,
    uint2* __restrict__ cands, int* __restrict__ counts,
    int S, int base,
    float aw0, float ah0, float aw1, float ah1, float aw2, float ah2)
{
    int i = blockIdx.x * 256 + threadIdx.x;
    int n = S * S * 3;
    if (i >= n) return;

    int a = i % 3;
    int cell = i / 3;
    int gx = cell % S;
    int gy = cell / S;

    const float* f = feats + (size_t)i * 85;
    float tx = f[0], ty = f[1], tw = f[2], th = f[3], tc = f[4];

    float Sf = (float)S;
    float inpf = Sf * 32.0f;
    float aw = (a == 0) ? aw0 : ((a == 1) ? aw1 : aw2);
    float ah = (a == 0) ? ah0 : ((a == 1) ? ah1 : ah2);

    // yolo_head
    float x = (sigf(tx) + (float)gx) / Sf;
    float y = (sigf(ty) + (float)gy) / Sf;
    float w = expf(tw) * aw / inpf;
    float h = expf(th) * ah / inpf;

    // yolo_correct_boxes (letterbox constants identical for both layers):
    // offset = [0.21875, 0], scale = [3072/1728, 1]
    const float OFF = 0.21875f;
    const float SC  = 3072.0f / 1728.0f;
    float yy = (y - OFF) * SC;
    float hh = h * SC;

    float ymin = (yy - hh * 0.5f) * 1080.0f;
    float xmin = (x  - w  * 0.5f) * 1920.0f;
    float ymax = (yy + hh * 0.5f) * 1080.0f;
    float xmax = (x  + w  * 0.5f) * 1920.0f;

    int gi = base + i;
    boxes[gi] = make_float4(ymin, xmin, ymax, xmax);

    float sconf = sigf(tc);
    // sconf < 0.6 => sconf*sigmoid(p) <= sconf < 0.6 for all classes (exact).
    if (sconf >= 0.6f) {
        for (int c = 0; c < NCLS; ++c) {
            float p = f[5 + c];
            float s = sconf * sigf(p);
            if (s >= 0.6f) {
                int pos = atomicAdd(&counts[c], 1);
                if (pos < CAP) {
                    cands[(size_t)c * CAP + pos] =
                        make_uint2(__float_as_uint(s), (unsigned)gi);
                }
            }
        }
    }
}

// One block per class. Greedy NMS over compacted candidates in LDS.
// Tie-break on original index reproduces jnp.argmax first-max semantics.
__global__ __launch_bounds__(256) void nms_kernel(
    const float4* __restrict__ boxes, const uint2* __restrict__ cands,
    const int* __restrict__ counts, float* __restrict__ out)
{
    __shared__ float s_sc[LCAP];
    __shared__ int   s_ix[LCAP];
    __shared__ float pw_s[4];
    __shared__ int   pw_i[4];
    __shared__ float bc_s;
    __shared__ int   bc_i;

    int c = blockIdx.x;
    int tid = threadIdx.x;

    int cnt = counts[c];
    if (cnt > CAP)  cnt = CAP;
    if (cnt > LCAP) cnt = LCAP;

    const uint2* cl = cands + (size_t)c * CAP;
    for (int e = tid; e < cnt; e += 256) {
        uint2 v = cl[e];
        s_sc[e] = __uint_as_float(v.x);
        s_ix[e] = (int)v.y;
    }
    __syncthreads();

    float* ob  = out;             // 1600 boxes * 4
    float* os  = out + 6400;      // 1600 scores
    float* ocl = out + 8000;      // 1600 classes (as float)

    int r = 0;
    for (; r < MAXB; ++r) {
        // ---- argmax with (score desc, idx asc) ordering ----
        float bs = -2.0f;
        int   bi = 0x7fffffff;
        for (int e = tid; e < cnt; e += 256) {
            float s = s_sc[e];
            int  ix = s_ix[e];
            if (s > bs || (s == bs && ix < bi)) { bs = s; bi = ix; }
        }
        // wave (64-lane) reduce
        for (int off = 32; off > 0; off >>= 1) {
            float s2 = __shfl_down(bs, off);
            int   i2 = __shfl_down(bi, off);
            if (s2 > bs || (s2 == bs && i2 < bi)) { bs = s2; bi = i2; }
        }
        if ((tid & 63) == 0) { pw_s[tid >> 6] = bs; pw_i[tid >> 6] = bi; }
        __syncthreads();
        if (tid == 0) {
            float s0 = pw_s[0]; int i0 = pw_i[0];
            for (int k = 1; k < 4; ++k) {
                float s2 = pw_s[k]; int i2 = pw_i[k];
                if (s2 > s0 || (s2 == s0 && i2 < i0)) { s0 = s2; i0 = i2; }
            }
            bc_s = s0; bc_i = i0;
        }
        __syncthreads();
        float best_s = bc_s;
        int   best_i = bc_i;

        if (best_s < 0.6f) break;   // nothing valid remains (uniform)

        float4 sb = boxes[best_i];
        float area_s = (sb.z - sb.x) * (sb.w - sb.y);

        if (tid == 0) {
            int o = c * MAXB + r;
            ob[o * 4 + 0] = sb.x;
            ob[o * 4 + 1] = sb.y;
            ob[o * 4 + 2] = sb.z;
            ob[o * 4 + 3] = sb.w;
            os[o]  = best_s;
            ocl[o] = (float)c;
        }

        // ---- suppression ----
        for (int e = tid; e < cnt; e += 256) {
            float s = s_sc[e];
            if (s < 0.6f) continue;   // already dead
            int ix = s_ix[e];
            float4 cb = boxes[ix];
            float y1 = fmaxf(sb.x, cb.x);
            float x1 = fmaxf(sb.y, cb.y);
            float y2 = fminf(sb.z, cb.z);
            float x2 = fminf(sb.w, cb.w);
            float ih = fmaxf(y2 - y1, 0.0f);
            float iw = fmaxf(x2 - x1, 0.0f);
            float inter = ih * iw;
            float area_c = (cb.z - cb.x) * (cb.w - cb.y);
            float un = area_s + area_c - inter;
            float iou = (un > 0.0f) ? (inter / un) : 0.0f;
            if (iou > 0.5f || ix == best_i) s_sc[e] = -1.0f;
        }
        __syncthreads();
    }

    // remaining (invalid) slots: zero boxes/scores, class = -1
    for (int q = r + tid; q < MAXB; q += 256) {
        int o = c * MAXB + q;
        ob[o * 4 + 0] = 0.0f;
        ob[o * 4 + 1] = 0.0f;
        ob[o * 4 + 2] = 0.0f;
        ob[o * 4 + 3] = 0.0f;
        os[o]  = 0.0f;
        ocl[o] = -1.0f;
    }
}

extern "C" void kernel_launch(void* const* d_in, const int* in_sizes, int n_in,
                              void* d_out, int out_size, void* d_ws, size_t ws_size,
                              hipStream_t stream) {
    const float* feats0 = (const float*)d_in[0];
    const float* feats1 = (const float*)d_in[1];
    float* out = (float*)d_out;

    char* ws = (char*)d_ws;
    float4* boxes = (float4*)ws;                       // NTOT * 16B = 2,211,840
    int*    counts = (int*)(ws + 2211840);             // 80 * 4B
    uint2*  cands  = (uint2*)(ws + 2211840 + 1024);    // 80 * CAP * 8B = 5.24MB

    init_counts<<<1, 128, 0, stream>>>(counts);

    decode_kernel<<<N0 / 256, 256, 0, stream>>>(
        feats0, boxes, cands, counts, 96, 0,
        81.0f, 82.0f, 135.0f, 169.0f, 344.0f, 319.0f);
    decode_kernel<<<N1 / 256, 256, 0, stream>>>(
        feats1, boxes, cands, counts, 192, N0,
        23.0f, 27.0f, 37.0f, 58.0f, 81.0f, 82.0f);

    nms_kernel<<<NCLS, 256, 0, stream>>>(boxes, cands, counts, out);
}

// Round 2
// 239.133 us; speedup vs baseline: 5.8949x; 5.8949x over previous
//
#include <hip/hip_runtime.h>

#define NCLS 80
#define MAXB 20
#define N0 27648     // 96*96*3
#define N1 110592    // 192*192*3
#define NTOT (N0 + N1)
#define CAP 8192       // per-class candidate capacity in workspace
#define LCAP 7680      // per-class candidate capacity in NMS LDS
#define BLK_STAGE 2048 // per-block staging capacity (expected ~350)
#define CNT_STRIDE 16  // pad class counters to one 64B line each

__device__ __forceinline__ float sigf(float x) {
    return 1.0f / (1.0f + expf(-x));
}

__global__ __launch_bounds__(256) void init_counts(int* counts) {
    int t = blockIdx.x * 256 + threadIdx.x;
    if (t < NCLS * CNT_STRIDE) counts[t] = 0;
}

// One thread per anchor. Decode box; conf-gate the 80-class loop; stage
// candidates in LDS; reserve per-class global slices with ONE atomic per
// (block,class); scatter. Kills the global-atomic serialization that made
// round-1 decode take 990us (VALUBusy 0.9%).
__global__ __launch_bounds__(256) void decode_kernel(
    const float* __restrict__ feats, float4* __restrict__ boxes,
    uint2* __restrict__ cands, int* __restrict__ counts,
    int S, int base,
    float aw0, float ah0, float aw1, float ah1, float aw2, float ah2)
{
    __shared__ float    s_sc[BLK_STAGE];
    __shared__ unsigned s_pk[BLK_STAGE];   // gi | (class<<18)
    __shared__ int s_n;
    __shared__ int s_cnt[NCLS];
    __shared__ int s_base[NCLS];

    int tid = threadIdx.x;
    if (tid == 0) s_n = 0;
    for (int c = tid; c < NCLS; c += 256) s_cnt[c] = 0;
    __syncthreads();

    int i = blockIdx.x * 256 + tid;   // grids are exact multiples of 256

    int a = i % 3;
    int cell = i / 3;
    int gx = cell % S;
    int gy = cell / S;

    const float* f = feats + (size_t)i * 85;
    float tx = f[0], ty = f[1], tw = f[2], th = f[3], tc = f[4];

    float Sf = (float)S;
    float inpf = Sf * 32.0f;
    float aw = (a == 0) ? aw0 : ((a == 1) ? aw1 : aw2);
    float ah = (a == 0) ? ah0 : ((a == 1) ? ah1 : ah2);

    // yolo_head
    float x = (sigf(tx) + (float)gx) / Sf;
    float y = (sigf(ty) + (float)gy) / Sf;
    float w = expf(tw) * aw / inpf;
    float h = expf(th) * ah / inpf;

    // yolo_correct_boxes: letterbox constants identical for both layers
    const float OFF = 0.21875f;
    const float SC  = 3072.0f / 1728.0f;
    float yy = (y - OFF) * SC;
    float hh = h * SC;

    float ymin = (yy - hh * 0.5f) * 1080.0f;
    float xmin = (x  - w  * 0.5f) * 1920.0f;
    float ymax = (yy + hh * 0.5f) * 1080.0f;
    float xmax = (x  + w  * 0.5f) * 1920.0f;

    int gi = base + i;
    boxes[gi] = make_float4(ymin, xmin, ymax, xmax);

    float sconf = sigf(tc);
    // sconf < 0.6 => sconf*sigmoid(p) < 0.6 for all classes (exact bound).
    if (sconf >= 0.6f) {
        for (int c = 0; c < NCLS; ++c) {
            float s = sconf * sigf(f[5 + c]);
            if (s >= 0.6f) {
                int p = atomicAdd(&s_n, 1);   // LDS atomic: cheap
                if (p < BLK_STAGE) {
                    s_sc[p] = s;
                    s_pk[p] = (unsigned)gi | ((unsigned)c << 18);
                }
            }
        }
    }
    __syncthreads();

    int n = s_n < BLK_STAGE ? s_n : BLK_STAGE;

    // per-class block totals
    for (int e = tid; e < n; e += 256)
        atomicAdd(&s_cnt[s_pk[e] >> 18], 1);
    __syncthreads();

    // one global atomic per (block,class) with count>0, to a padded line
    for (int c = tid; c < NCLS; c += 256) {
        int k = s_cnt[c];
        s_base[c] = (k > 0) ? atomicAdd(&counts[c * CNT_STRIDE], k) : 0;
        s_cnt[c] = 0;
    }
    __syncthreads();

    // scatter into reserved slices
    for (int e = tid; e < n; e += 256) {
        unsigned pk = s_pk[e];
        int c = pk >> 18;
        int lpos = atomicAdd(&s_cnt[c], 1);   // LDS atomic
        int pos = s_base[c] + lpos;
        if (pos < CAP)
            cands[(size_t)c * CAP + pos] =
                make_uint2(__float_as_uint(s_sc[e]), pk & 0x3FFFFu);
    }
}

// One block per class. Greedy NMS over compacted candidates in LDS.
// Tie-break on original index reproduces jnp.argmax first-max semantics
// regardless of candidate arrival order.
__global__ __launch_bounds__(256) void nms_kernel(
    const float4* __restrict__ boxes, const uint2* __restrict__ cands,
    const int* __restrict__ counts, float* __restrict__ out)
{
    __shared__ float s_sc[LCAP];
    __shared__ int   s_ix[LCAP];
    __shared__ float pw_s[4];
    __shared__ int   pw_i[4];
    __shared__ float bc_s;
    __shared__ int   bc_i;

    int c = blockIdx.x;
    int tid = threadIdx.x;

    int cnt = counts[c * CNT_STRIDE];
    if (cnt > CAP)  cnt = CAP;
    if (cnt > LCAP) cnt = LCAP;

    const uint2* cl = cands + (size_t)c * CAP;
    for (int e = tid; e < cnt; e += 256) {
        uint2 v = cl[e];
        s_sc[e] = __uint_as_float(v.x);
        s_ix[e] = (int)v.y;
    }
    __syncthreads();

    float* ob  = out;             // 1600 boxes * 4
    float* os  = out + 6400;      // 1600 scores
    float* ocl = out + 8000;      // 1600 classes (as float)

    int r = 0;
    for (; r < MAXB; ++r) {
        // ---- argmax with (score desc, idx asc) ordering ----
        float bs = -2.0f;
        int   bi = 0x7fffffff;
        for (int e = tid; e < cnt; e += 256) {
            float s = s_sc[e];
            int  ix = s_ix[e];
            if (s > bs || (s == bs && ix < bi)) { bs = s; bi = ix; }
        }
        for (int off = 32; off > 0; off >>= 1) {
            float s2 = __shfl_down(bs, off);
            int   i2 = __shfl_down(bi, off);
            if (s2 > bs || (s2 == bs && i2 < bi)) { bs = s2; bi = i2; }
        }
        if ((tid & 63) == 0) { pw_s[tid >> 6] = bs; pw_i[tid >> 6] = bi; }
        __syncthreads();
        if (tid == 0) {
            float s0 = pw_s[0]; int i0 = pw_i[0];
            for (int k = 1; k < 4; ++k) {
                float s2 = pw_s[k]; int i2 = pw_i[k];
                if (s2 > s0 || (s2 == s0 && i2 < i0)) { s0 = s2; i0 = i2; }
            }
            bc_s = s0; bc_i = i0;
        }
        __syncthreads();
        float best_s = bc_s;
        int   best_i = bc_i;

        if (best_s < 0.6f) break;   // nothing valid remains (uniform exit)

        float4 sb = boxes[best_i];
        float area_s = (sb.z - sb.x) * (sb.w - sb.y);

        if (tid == 0) {
            int o = c * MAXB + r;
            ob[o * 4 + 0] = sb.x;
            ob[o * 4 + 1] = sb.y;
            ob[o * 4 + 2] = sb.z;
            ob[o * 4 + 3] = sb.w;
            os[o]  = best_s;
            ocl[o] = (float)c;
        }

        // ---- suppression ----
        for (int e = tid; e < cnt; e += 256) {
            float s = s_sc[e];
            if (s < 0.6f) continue;   // already dead
            int ix = s_ix[e];
            float4 cb = boxes[ix];
            float y1 = fmaxf(sb.x, cb.x);
            float x1 = fmaxf(sb.y, cb.y);
            float y2 = fminf(sb.z, cb.z);
            float x2 = fminf(sb.w, cb.w);
            float ih = fmaxf(y2 - y1, 0.0f);
            float iw = fmaxf(x2 - x1, 0.0f);
            float inter = ih * iw;
            float area_c = (cb.z - cb.x) * (cb.w - cb.y);
            float un = area_s + area_c - inter;
            float iou = (un > 0.0f) ? (inter / un) : 0.0f;
            if (iou > 0.5f || ix == best_i) s_sc[e] = -1.0f;
        }
        __syncthreads();
    }

    // remaining (invalid) slots: zero boxes/scores, class = -1
    for (int q = r + tid; q < MAXB; q += 256) {
        int o = c * MAXB + q;
        ob[o * 4 + 0] = 0.0f;
        ob[o * 4 + 1] = 0.0f;
        ob[o * 4 + 2] = 0.0f;
        ob[o * 4 + 3] = 0.0f;
        os[o]  = 0.0f;
        ocl[o] = -1.0f;
    }
}

extern "C" void kernel_launch(void* const* d_in, const int* in_sizes, int n_in,
                              void* d_out, int out_size, void* d_ws, size_t ws_size,
                              hipStream_t stream) {
    const float* feats0 = (const float*)d_in[0];
    const float* feats1 = (const float*)d_in[1];
    float* out = (float*)d_out;

    char* ws = (char*)d_ws;
    float4* boxes = (float4*)ws;                       // NTOT*16B = 2,211,840
    int*    counts = (int*)(ws + 2211840);             // 80*16*4B = 5,120
    uint2*  cands  = (uint2*)(ws + 2211840 + 8192);    // 80*CAP*8B = 5.24MB

    init_counts<<<(NCLS * CNT_STRIDE + 255) / 256, 256, 0, stream>>>(counts);

    decode_kernel<<<N0 / 256, 256, 0, stream>>>(
        feats0, boxes, cands, counts, 96, 0,
        81.0f, 82.0f, 135.0f, 169.0f, 344.0f, 319.0f);
    decode_kernel<<<N1 / 256, 256, 0, stream>>>(
        feats1, boxes, cands, counts, 192, N0,
        23.0f, 27.0f, 37.0f, 58.0f, 81.0f, 82.0f);

    nms_kernel<<<NCLS, 256, 0, stream>>>(boxes, cands, counts, out);
}

// Round 3
// 156.345 us; speedup vs baseline: 9.0163x; 1.5295x over previous
//
#include <hip/hip_runtime.h>

#define NCLS 80
#define MAXB 20
#define N0 27648     // 96*96*3
#define N1 110592    // 192*192*3
#define NTOT (N0 + N1)
#define CAP 8192       // per-class candidate capacity in workspace
#define BLK_STAGE 2048 // per-block staging capacity in decode
#define CNT_STRIDE 16  // pad class counters to one 64B line each
#define K_STRIPE 24    // candidates per thread in NMS registers
#define NCAP (K_STRIPE * 256)   // 6144; expected cnt ~3790 +- 61

__device__ __forceinline__ float sigf(float x) {
    return 1.0f / (1.0f + expf(-x));
}

__global__ __launch_bounds__(256) void init_counts(int* counts) {
    int t = blockIdx.x * 256 + threadIdx.x;
    if (t < NCLS * CNT_STRIDE) counts[t] = 0;
}

// One thread per anchor. Decode box; conf-gate the 80-class loop; stage
// candidates in LDS; reserve per-class global slices with ONE atomic per
// (block,class); scatter.
__global__ __launch_bounds__(256) void decode_kernel(
    const float* __restrict__ feats, float4* __restrict__ boxes,
    uint2* __restrict__ cands, int* __restrict__ counts,
    int S, int base,
    float aw0, float ah0, float aw1, float ah1, float aw2, float ah2)
{
    __shared__ float    s_sc[BLK_STAGE];
    __shared__ unsigned s_pk[BLK_STAGE];   // gi | (class<<18)
    __shared__ int s_n;
    __shared__ int s_cnt[NCLS];
    __shared__ int s_base[NCLS];

    int tid = threadIdx.x;
    if (tid == 0) s_n = 0;
    for (int c = tid; c < NCLS; c += 256) s_cnt[c] = 0;
    __syncthreads();

    int i = blockIdx.x * 256 + tid;   // grids are exact multiples of 256

    int a = i % 3;
    int cell = i / 3;
    int gx = cell % S;
    int gy = cell / S;

    const float* f = feats + (size_t)i * 85;
    float tx = f[0], ty = f[1], tw = f[2], th = f[3], tc = f[4];

    float Sf = (float)S;
    float inpf = Sf * 32.0f;
    float aw = (a == 0) ? aw0 : ((a == 1) ? aw1 : aw2);
    float ah = (a == 0) ? ah0 : ((a == 1) ? ah1 : ah2);

    // yolo_head
    float x = (sigf(tx) + (float)gx) / Sf;
    float y = (sigf(ty) + (float)gy) / Sf;
    float w = expf(tw) * aw / inpf;
    float h = expf(th) * ah / inpf;

    // yolo_correct_boxes: letterbox constants identical for both layers
    const float OFF = 0.21875f;
    const float SC  = 3072.0f / 1728.0f;
    float yy = (y - OFF) * SC;
    float hh = h * SC;

    float ymin = (yy - hh * 0.5f) * 1080.0f;
    float xmin = (x  - w  * 0.5f) * 1920.0f;
    float ymax = (yy + hh * 0.5f) * 1080.0f;
    float xmax = (x  + w  * 0.5f) * 1920.0f;

    int gi = base + i;
    boxes[gi] = make_float4(ymin, xmin, ymax, xmax);

    float sconf = sigf(tc);
    // sconf < 0.6 => sconf*sigmoid(p) < 0.6 for all classes (exact bound).
    if (sconf >= 0.6f) {
        for (int c = 0; c < NCLS; ++c) {
            float s = sconf * sigf(f[5 + c]);
            if (s >= 0.6f) {
                int p = atomicAdd(&s_n, 1);   // LDS atomic: cheap
                if (p < BLK_STAGE) {
                    s_sc[p] = s;
                    s_pk[p] = (unsigned)gi | ((unsigned)c << 18);
                }
            }
        }
    }
    __syncthreads();

    int n = s_n < BLK_STAGE ? s_n : BLK_STAGE;

    // per-class block totals
    for (int e = tid; e < n; e += 256)
        atomicAdd(&s_cnt[s_pk[e] >> 18], 1);
    __syncthreads();

    // one global atomic per (block,class) with count>0, to a padded line
    for (int c = tid; c < NCLS; c += 256) {
        int k = s_cnt[c];
        s_base[c] = (k > 0) ? atomicAdd(&counts[c * CNT_STRIDE], k) : 0;
        s_cnt[c] = 0;
    }
    __syncthreads();

    // scatter into reserved slices
    for (int e = tid; e < n; e += 256) {
        unsigned pk = s_pk[e];
        int c = pk >> 18;
        int lpos = atomicAdd(&s_cnt[c], 1);   // LDS atomic
        int pos = s_base[c] + lpos;
        if (pos < CAP)
            cands[(size_t)c * CAP + pos] =
                make_uint2(__float_as_uint(s_sc[e]), pk & 0x3FFFFu);
    }
}

// One block per class. Candidates fully register-resident (K_STRIPE per
// thread, statically indexed via full unroll). Per round: in-register argmax
// + shfl reduce + ONE syncthreads (double-buffered 4-slot scratch) +
// in-register suppression. Tie-break on original index keeps the result
// invariant to atomic compaction order.
__global__ __launch_bounds__(256) void nms_kernel(
    const float4* __restrict__ boxes, const uint2* __restrict__ cands,
    const int* __restrict__ counts, float* __restrict__ out)
{
    __shared__ float pw_s[2][4];
    __shared__ int   pw_i[2][4];

    int c = blockIdx.x;
    int tid = threadIdx.x;

    int cnt = counts[c * CNT_STRIDE];
    if (cnt > CAP)  cnt = CAP;
    if (cnt > NCAP) cnt = NCAP;

    const uint2* cl = cands + (size_t)c * CAP;

    float  sc[K_STRIPE];
    int    ix[K_STRIPE];
    float4 bx[K_STRIPE];

#pragma unroll
    for (int k = 0; k < K_STRIPE; ++k) {
        int e = tid + k * 256;
        sc[k] = -1.0f;
        ix[k] = 0x7fffffff;
        bx[k] = make_float4(0.0f, 0.0f, 0.0f, 0.0f);
        if (e < cnt) {
            uint2 v = cl[e];
            sc[k] = __uint_as_float(v.x);
            ix[k] = (int)v.y;
            bx[k] = boxes[v.y];
        }
    }

    float* ob  = out;             // 1600 boxes * 4
    float* os  = out + 6400;      // 1600 scores
    float* ocl = out + 8000;      // 1600 classes (as float)

    int r = 0;
    for (; r < MAXB; ++r) {
        // ---- in-register argmax, (score desc, idx asc) ----
        float bs = -2.0f;
        int   bi = 0x7fffffff;
#pragma unroll
        for (int k = 0; k < K_STRIPE; ++k) {
            if (sc[k] > bs || (sc[k] == bs && ix[k] < bi)) { bs = sc[k]; bi = ix[k]; }
        }
        for (int off = 32; off > 0; off >>= 1) {
            float s2 = __shfl_down(bs, off);
            int   i2 = __shfl_down(bi, off);
            if (s2 > bs || (s2 == bs && i2 < bi)) { bs = s2; bi = i2; }
        }
        int p = r & 1;
        if ((tid & 63) == 0) { pw_s[p][tid >> 6] = bs; pw_i[p][tid >> 6] = bi; }
        __syncthreads();   // only sync this round (pw double-buffered)

        float best_s = pw_s[p][0];
        int   best_i = pw_i[p][0];
        for (int w = 1; w < 4; ++w) {
            float s2 = pw_s[p][w];
            int   i2 = pw_i[p][w];
            if (s2 > best_s || (s2 == best_s && i2 < best_i)) { best_s = s2; best_i = i2; }
        }

        if (best_s < 0.6f) break;   // uniform exit

        float4 sb = boxes[best_i];  // same-address broadcast load (L2)
        float area_s = (sb.z - sb.x) * (sb.w - sb.y);

        if (tid == 0) {
            int o = c * MAXB + r;
            ob[o * 4 + 0] = sb.x;
            ob[o * 4 + 1] = sb.y;
            ob[o * 4 + 2] = sb.z;
            ob[o * 4 + 3] = sb.w;
            os[o]  = best_s;
            ocl[o] = (float)c;
        }

        // ---- in-register suppression ----
#pragma unroll
        for (int k = 0; k < K_STRIPE; ++k) {
            if (sc[k] >= 0.6f) {
                float y1 = fmaxf(sb.x, bx[k].x);
                float x1 = fmaxf(sb.y, bx[k].y);
                float y2 = fminf(sb.z, bx[k].z);
                float x2 = fminf(sb.w, bx[k].w);
                float ih = fmaxf(y2 - y1, 0.0f);
                float iw = fmaxf(x2 - x1, 0.0f);
                float inter = ih * iw;
                float area_c = (bx[k].z - bx[k].x) * (bx[k].w - bx[k].y);
                float un = area_s + area_c - inter;
                float iou = (un > 0.0f) ? (inter / un) : 0.0f;
                if (iou > 0.5f || ix[k] == best_i) sc[k] = -1.0f;
            }
        }
    }

    // remaining (invalid) slots: zero boxes/scores, class = -1
    for (int q = r + tid; q < MAXB; q += 256) {
        int o = c * MAXB + q;
        ob[o * 4 + 0] = 0.0f;
        ob[o * 4 + 1] = 0.0f;
        ob[o * 4 + 2] = 0.0f;
        ob[o * 4 + 3] = 0.0f;
        os[o]  = 0.0f;
        ocl[o] = -1.0f;
    }
}

extern "C" void kernel_launch(void* const* d_in, const int* in_sizes, int n_in,
                              void* d_out, int out_size, void* d_ws, size_t ws_size,
                              hipStream_t stream) {
    const float* feats0 = (const float*)d_in[0];
    const float* feats1 = (const float*)d_in[1];
    float* out = (float*)d_out;

    char* ws = (char*)d_ws;
    float4* boxes = (float4*)ws;                       // NTOT*16B = 2,211,840
    int*    counts = (int*)(ws + 2211840);             // 80*16*4B
    uint2*  cands  = (uint2*)(ws + 2211840 + 8192);    // 80*CAP*8B = 5.24MB

    init_counts<<<(NCLS * CNT_STRIDE + 255) / 256, 256, 0, stream>>>(counts);

    decode_kernel<<<N0 / 256, 256, 0, stream>>>(
        feats0, boxes, cands, counts, 96, 0,
        81.0f, 82.0f, 135.0f, 169.0f, 344.0f, 319.0f);
    decode_kernel<<<N1 / 256, 256, 0, stream>>>(
        feats1, boxes, cands, counts, 192, N0,
        23.0f, 27.0f, 37.0f, 58.0f, 81.0f, 82.0f);

    nms_kernel<<<NCLS, 256, 0, stream>>>(boxes, cands, counts, out);
}

// Round 4
// 141.105 us; speedup vs baseline: 9.9901x; 1.1080x over previous
//
#include <hip/hip_runtime.h>

#define NCLS 80
#define MAXB 20
#define N0 27648     // 96*96*3
#define N1 110592    // 192*192*3
#define NTOT (N0 + N1)
#define CAP 8192       // per-class candidate capacity in workspace
#define BLK_STAGE 2048 // per-block staging capacity in decode
#define CNT_STRIDE 16  // pad class counters to one 64B line each
#define NMS_T 1024     // NMS block size (16 waves -> 4 waves/SIMD)
#define NMS_W 16
#define NMS_K 6        // candidates per thread
#define NCAP (NMS_T * NMS_K)   // 6144; expected cnt ~3790 +- 61

__device__ __forceinline__ float sigf(float x) {
    return 1.0f / (1.0f + expf(-x));
}

__device__ __forceinline__ unsigned long long max64(unsigned long long a,
                                                   unsigned long long b) {
    return a > b ? a : b;
}

__device__ __forceinline__ unsigned long long shflxor64(unsigned long long v, int m) {
    unsigned hi = __shfl_xor((unsigned)(v >> 32), m);
    unsigned lo = __shfl_xor((unsigned)v, m);
    return ((unsigned long long)hi << 32) | lo;
}

__global__ __launch_bounds__(256) void init_counts(int* counts) {
    int t = blockIdx.x * 256 + threadIdx.x;
    if (t < NCLS * CNT_STRIDE) counts[t] = 0;
}

// One thread per anchor. Decode box; conf-gate the 80-class loop; stage
// candidates in LDS; reserve per-class global slices with ONE atomic per
// (block,class); scatter.
__global__ __launch_bounds__(256) void decode_kernel(
    const float* __restrict__ feats, float4* __restrict__ boxes,
    uint2* __restrict__ cands, int* __restrict__ counts,
    int S, int base,
    float aw0, float ah0, float aw1, float ah1, float aw2, float ah2)
{
    __shared__ float    s_sc[BLK_STAGE];
    __shared__ unsigned s_pk[BLK_STAGE];   // gi | (class<<18)
    __shared__ int s_n;
    __shared__ int s_cnt[NCLS];
    __shared__ int s_base[NCLS];

    int tid = threadIdx.x;
    if (tid == 0) s_n = 0;
    for (int c = tid; c < NCLS; c += 256) s_cnt[c] = 0;
    __syncthreads();

    int i = blockIdx.x * 256 + tid;   // grids are exact multiples of 256

    int a = i % 3;
    int cell = i / 3;
    int gx = cell % S;
    int gy = cell / S;

    const float* f = feats + (size_t)i * 85;
    float tx = f[0], ty = f[1], tw = f[2], th = f[3], tc = f[4];

    float Sf = (float)S;
    float inpf = Sf * 32.0f;
    float aw = (a == 0) ? aw0 : ((a == 1) ? aw1 : aw2);
    float ah = (a == 0) ? ah0 : ((a == 1) ? ah1 : ah2);

    // yolo_head
    float x = (sigf(tx) + (float)gx) / Sf;
    float y = (sigf(ty) + (float)gy) / Sf;
    float w = expf(tw) * aw / inpf;
    float h = expf(th) * ah / inpf;

    // yolo_correct_boxes: letterbox constants identical for both layers
    const float OFF = 0.21875f;
    const float SC  = 3072.0f / 1728.0f;
    float yy = (y - OFF) * SC;
    float hh = h * SC;

    float ymin = (yy - hh * 0.5f) * 1080.0f;
    float xmin = (x  - w  * 0.5f) * 1920.0f;
    float ymax = (yy + hh * 0.5f) * 1080.0f;
    float xmax = (x  + w  * 0.5f) * 1920.0f;

    int gi = base + i;
    boxes[gi] = make_float4(ymin, xmin, ymax, xmax);

    float sconf = sigf(tc);
    // sconf < 0.6 => sconf*sigmoid(p) < 0.6 for all classes (exact bound).
    if (sconf >= 0.6f) {
        for (int c = 0; c < NCLS; ++c) {
            float s = sconf * sigf(f[5 + c]);
            if (s >= 0.6f) {
                int p = atomicAdd(&s_n, 1);   // LDS atomic: cheap
                if (p < BLK_STAGE) {
                    s_sc[p] = s;
                    s_pk[p] = (unsigned)gi | ((unsigned)c << 18);
                }
            }
        }
    }
    __syncthreads();

    int n = s_n < BLK_STAGE ? s_n : BLK_STAGE;

    // per-class block totals
    for (int e = tid; e < n; e += 256)
        atomicAdd(&s_cnt[s_pk[e] >> 18], 1);
    __syncthreads();

    // one global atomic per (block,class) with count>0, to a padded line
    for (int c = tid; c < NCLS; c += 256) {
        int k = s_cnt[c];
        s_base[c] = (k > 0) ? atomicAdd(&counts[c * CNT_STRIDE], k) : 0;
        s_cnt[c] = 0;
    }
    __syncthreads();

    // scatter into reserved slices
    for (int e = tid; e < n; e += 256) {
        unsigned pk = s_pk[e];
        int c = pk >> 18;
        int lpos = atomicAdd(&s_cnt[c], 1);   // LDS atomic
        int pos = s_base[c] + lpos;
        if (pos < CAP)
            cands[(size_t)c * CAP + pos] =
                make_uint2(__float_as_uint(s_sc[e]), pk & 0x3FFFFu);
    }
}

// One block (1024 thr, 16 waves) per class. Candidates register-resident,
// key = (score_bits<<32)|~idx so (score desc, idx asc) argmax == u64 max.
// Per round: 5-op register tree max + 6-step shfl_xor butterfly (all lanes
// get wave-best) + owner lane deposits its box in LDS + ONE barrier
// (double-buffered slots) + redundant 16-way combine + in-register
// suppression. No global memory in the round loop.
__global__ __launch_bounds__(NMS_T) void nms_kernel(
    const float4* __restrict__ boxes, const uint2* __restrict__ cands,
    const int* __restrict__ counts, float* __restrict__ out)
{
    __shared__ unsigned long long pk[2][NMS_W];
    __shared__ float4             pb[2][NMS_W];

    int c = blockIdx.x;
    int tid = threadIdx.x;
    int lane = tid & 63;
    int wv = tid >> 6;

    int cnt = counts[c * CNT_STRIDE];
    if (cnt > CAP)  cnt = CAP;
    if (cnt > NCAP) cnt = NCAP;

    const uint2* cl = cands + (size_t)c * CAP;

    unsigned long long key[NMS_K];
    float4 bx[NMS_K];
    float  ar[NMS_K];

#pragma unroll
    for (int k = 0; k < NMS_K; ++k) {
        int e = tid + k * NMS_T;
        key[k] = 0ull;
        bx[k] = make_float4(0.0f, 0.0f, 0.0f, 0.0f);
        ar[k] = 0.0f;
        if (e < cnt) {
            uint2 v = cl[e];
            key[k] = ((unsigned long long)v.x << 32) | (unsigned)(~v.y);
            bx[k] = boxes[v.y];
            ar[k] = (bx[k].z - bx[k].x) * (bx[k].w - bx[k].y);
        }
    }

    float* ob  = out;             // 1600 boxes * 4
    float* os  = out + 6400;      // 1600 scores
    float* ocl = out + 8000;      // 1600 classes (as float)

    int r = 0;
    for (; r < MAXB; ++r) {
        // ---- register tree max ----
        unsigned long long best =
            max64(max64(max64(key[0], key[1]), max64(key[2], key[3])),
                  max64(key[4], key[5]));
        // ---- wave butterfly: all lanes end with wave-best ----
#pragma unroll
        for (int m = 1; m < 64; m <<= 1)
            best = max64(best, shflxor64(best, m));

        int p = r & 1;
        if (lane == 0) pk[p][wv] = best;
        if (best != 0ull) {
            // unique owner deposits its box (keys are globally unique)
#pragma unroll
            for (int k = 0; k < NMS_K; ++k)
                if (key[k] == best) pb[p][wv] = bx[k];
        }
        __syncthreads();   // single barrier/round (slots double-buffered)

        unsigned long long gb = pk[p][0];
        int gw = 0;
#pragma unroll
        for (int w = 1; w < NMS_W; ++w) {
            unsigned long long t = pk[p][w];
            if (t > gb) { gb = t; gw = w; }
        }

        float best_s = __uint_as_float((unsigned)(gb >> 32));
        if (best_s < 0.6f) break;   // uniform exit (gb==0 -> 0.0)

        float4 sb = pb[p][gw];      // LDS broadcast read
        unsigned best_iu = ~(unsigned)gb;
        float area_s = (sb.z - sb.x) * (sb.w - sb.y);

        if (tid == 0) {
            int o = c * MAXB + r;
            ob[o * 4 + 0] = sb.x;
            ob[o * 4 + 1] = sb.y;
            ob[o * 4 + 2] = sb.z;
            ob[o * 4 + 3] = sb.w;
            os[o]  = best_s;
            ocl[o] = (float)c;
        }

        // ---- in-register suppression (reference IoU formula, exact) ----
#pragma unroll
        for (int k = 0; k < NMS_K; ++k) {
            if (key[k] != 0ull) {
                float y1 = fmaxf(sb.x, bx[k].x);
                float x1 = fmaxf(sb.y, bx[k].y);
                float y2 = fminf(sb.z, bx[k].z);
                float x2 = fminf(sb.w, bx[k].w);
                float ih = fmaxf(y2 - y1, 0.0f);
                float iw = fmaxf(x2 - x1, 0.0f);
                float inter = ih * iw;
                float un = area_s + ar[k] - inter;
                float iou = (un > 0.0f) ? (inter / un) : 0.0f;
                if (iou > 0.5f || (~(unsigned)key[k]) == best_iu)
                    key[k] = 0ull;
            }
        }
    }

    // remaining (invalid) slots: zero boxes/scores, class = -1
    for (int q = r + tid; q < MAXB; q += NMS_T) {
        int o = c * MAXB + q;
        ob[o * 4 + 0] = 0.0f;
        ob[o * 4 + 1] = 0.0f;
        ob[o * 4 + 2] = 0.0f;
        ob[o * 4 + 3] = 0.0f;
        os[o]  = 0.0f;
        ocl[o] = -1.0f;
    }
}

extern "C" void kernel_launch(void* const* d_in, const int* in_sizes, int n_in,
                              void* d_out, int out_size, void* d_ws, size_t ws_size,
                              hipStream_t stream) {
    const float* feats0 = (const float*)d_in[0];
    const float* feats1 = (const float*)d_in[1];
    float* out = (float*)d_out;

    char* ws = (char*)d_ws;
    float4* boxes = (float4*)ws;                       // NTOT*16B = 2,211,840
    int*    counts = (int*)(ws + 2211840);             // 80*16*4B
    uint2*  cands  = (uint2*)(ws + 2211840 + 8192);    // 80*CAP*8B = 5.24MB

    init_counts<<<(NCLS * CNT_STRIDE + 255) / 256, 256, 0, stream>>>(counts);

    decode_kernel<<<N0 / 256, 256, 0, stream>>>(
        feats0, boxes, cands, counts, 96, 0,
        81.0f, 82.0f, 135.0f, 169.0f, 344.0f, 319.0f);
    decode_kernel<<<N1 / 256, 256, 0, stream>>>(
        feats1, boxes, cands, counts, 192, N0,
        23.0f, 27.0f, 37.0f, 58.0f, 81.0f, 82.0f);

    nms_kernel<<<NCLS, NMS_T, 0, stream>>>(boxes, cands, counts, out);
}

// Round 5
// 108.016 us; speedup vs baseline: 13.0505x; 1.3063x over previous
//
#include <hip/hip_runtime.h>

#define NCLS 80
#define MAXB 20
#define N0 27648     // 96*96*3
#define N1 110592    // 192*192*3
#define NTOT (N0 + N1)
#define CAP 8192       // per-class candidate capacity in workspace
#define STAGE 1536     // per-block candidate staging (expected ~560, +13 sigma)
#define CNT_STRIDE 16  // pad class counters to one 64B line each
#define NMS_T 1024     // NMS block size (16 waves)
#define NMS_W 16
#define NMS_K 6        // candidates per thread
#define NCAP (NMS_T * NMS_K)   // 6144

__device__ __forceinline__ float sigf(float x) {
    return 1.0f / (1.0f + expf(-x));
}

// Wave64 max-reduce via DPP (row_shr 1/2/4/8 + row_bcast 15/31), result
// broadcast from lane 63. Pure VALU (~30cy) vs ds_bpermute butterfly (~1.4k cy).
// old=x => invalid-source lanes keep x (identity under max/min).
__device__ __forceinline__ unsigned wave_max_bcast(unsigned x) {
    unsigned t;
    t = (unsigned)__builtin_amdgcn_update_dpp((int)x, (int)x, 0x111, 0xF, 0xF, false); x = x > t ? x : t;
    t = (unsigned)__builtin_amdgcn_update_dpp((int)x, (int)x, 0x112, 0xF, 0xF, false); x = x > t ? x : t;
    t = (unsigned)__builtin_amdgcn_update_dpp((int)x, (int)x, 0x114, 0xF, 0xF, false); x = x > t ? x : t;
    t = (unsigned)__builtin_amdgcn_update_dpp((int)x, (int)x, 0x118, 0xF, 0xF, false); x = x > t ? x : t;
    t = (unsigned)__builtin_amdgcn_update_dpp((int)x, (int)x, 0x142, 0xF, 0xF, false); x = x > t ? x : t;
    t = (unsigned)__builtin_amdgcn_update_dpp((int)x, (int)x, 0x143, 0xF, 0xF, false); x = x > t ? x : t;
    return (unsigned)__builtin_amdgcn_readlane((int)x, 63);
}

__device__ __forceinline__ unsigned wave_min_bcast(unsigned x) {
    unsigned t;
    t = (unsigned)__builtin_amdgcn_update_dpp((int)x, (int)x, 0x111, 0xF, 0xF, false); x = x < t ? x : t;
    t = (unsigned)__builtin_amdgcn_update_dpp((int)x, (int)x, 0x112, 0xF, 0xF, false); x = x < t ? x : t;
    t = (unsigned)__builtin_amdgcn_update_dpp((int)x, (int)x, 0x114, 0xF, 0xF, false); x = x < t ? x : t;
    t = (unsigned)__builtin_amdgcn_update_dpp((int)x, (int)x, 0x118, 0xF, 0xF, false); x = x < t ? x : t;
    t = (unsigned)__builtin_amdgcn_update_dpp((int)x, (int)x, 0x142, 0xF, 0xF, false); x = x < t ? x : t;
    t = (unsigned)__builtin_amdgcn_update_dpp((int)x, (int)x, 0x143, 0xF, 0xF, false); x = x < t ? x : t;
    return (unsigned)__builtin_amdgcn_readlane((int)x, 63);
}

__global__ __launch_bounds__(256) void init_counts(int* counts) {
    int t = blockIdx.x * 256 + threadIdx.x;
    if (t < NCLS * CNT_STRIDE) counts[t] = 0;
}

// Phase 0: per-thread box decode + conf gate; passing anchors compacted into
// an LDS pass-list. Phase 1: npass*80 (anchor,class) work-items distributed
// densely over all 256 threads (full lane utilization, coalesced prob loads).
// Phases 2-4: per-class counts -> one global reserve atomic per (block,class)
// -> scatter. Identical arithmetic & key packing to the proven version.
__global__ __launch_bounds__(256) void decode_kernel(
    const float* __restrict__ feats, float4* __restrict__ boxes,
    uint2* __restrict__ cands, int* __restrict__ counts,
    int S, int base,
    float aw0, float ah0, float aw1, float ah1, float aw2, float ah2)
{
    __shared__ unsigned p_gi[256];
    __shared__ float    p_conf[256];
    __shared__ int s_npass;
    __shared__ float    s_esc[STAGE];
    __shared__ unsigned s_ent[STAGE];   // gi | (class<<18)
    __shared__ int s_n;
    __shared__ int s_cnt[NCLS];
    __shared__ int s_base[NCLS];

    int tid = threadIdx.x;
    if (tid == 0) { s_npass = 0; s_n = 0; }
    for (int c = tid; c < NCLS; c += 256) s_cnt[c] = 0;
    __syncthreads();

    int i = blockIdx.x * 256 + tid;   // grids are exact multiples of 256

    int a = i % 3;
    int cell = i / 3;
    int gx = cell % S;
    int gy = cell / S;

    const float* f = feats + (size_t)i * 85;
    float tx = f[0], ty = f[1], tw = f[2], th = f[3], tc = f[4];

    float Sf = (float)S;
    float inpf = Sf * 32.0f;
    float aw = (a == 0) ? aw0 : ((a == 1) ? aw1 : aw2);
    float ah = (a == 0) ? ah0 : ((a == 1) ? ah1 : ah2);

    // yolo_head
    float x = (sigf(tx) + (float)gx) / Sf;
    float y = (sigf(ty) + (float)gy) / Sf;
    float w = expf(tw) * aw / inpf;
    float h = expf(th) * ah / inpf;

    // yolo_correct_boxes: letterbox constants identical for both layers
    const float OFF = 0.21875f;
    const float SC  = 3072.0f / 1728.0f;
    float yy = (y - OFF) * SC;
    float hh = h * SC;

    float ymin = (yy - hh * 0.5f) * 1080.0f;
    float xmin = (x  - w  * 0.5f) * 1920.0f;
    float ymax = (yy + hh * 0.5f) * 1080.0f;
    float xmax = (x  + w  * 0.5f) * 1920.0f;

    int gi = base + i;
    boxes[gi] = make_float4(ymin, xmin, ymax, xmax);

    float sconf = sigf(tc);
    // sconf < 0.6 => sconf*sigmoid(p) < 0.6 for all classes (exact bound).
    if (sconf >= 0.6f) {
        int sl = atomicAdd(&s_npass, 1);   // <= 256, cannot overflow
        p_gi[sl] = (unsigned)gi;
        p_conf[sl] = sconf;
    }
    __syncthreads();

    // dense emission over (pass-anchor, class) pairs; coalesced prob loads
    int tot = s_npass * NCLS;
    for (int wk = tid; wk < tot; wk += 256) {
        int sl = wk / NCLS;
        int c  = wk - sl * NCLS;
        float pv = feats[(size_t)(p_gi[sl] - (unsigned)base) * 85 + 5 + c];
        float s = p_conf[sl] * sigf(pv);
        if (s >= 0.6f) {
            int e = atomicAdd(&s_n, 1);   // LDS atomic (compiler wave-aggregates)
            if (e < STAGE) {
                s_esc[e] = s;
                s_ent[e] = p_gi[sl] | ((unsigned)c << 18);
            }
        }
    }
    __syncthreads();

    int n = s_n < STAGE ? s_n : STAGE;

    // per-class block totals
    for (int e = tid; e < n; e += 256)
        atomicAdd(&s_cnt[s_ent[e] >> 18], 1);
    __syncthreads();

    // one global atomic per (block,class) with count>0, to a padded line
    for (int c = tid; c < NCLS; c += 256) {
        int k = s_cnt[c];
        s_base[c] = (k > 0) ? atomicAdd(&counts[c * CNT_STRIDE], k) : 0;
        s_cnt[c] = 0;
    }
    __syncthreads();

    // scatter into reserved slices
    for (int e = tid; e < n; e += 256) {
        unsigned ent = s_ent[e];
        int c = ent >> 18;
        int lpos = atomicAdd(&s_cnt[c], 1);   // LDS atomic
        int pos = s_base[c] + lpos;
        if (pos < CAP)
            cands[(size_t)c * CAP + pos] =
                make_uint2(__float_as_uint(s_esc[e]), ent & 0x3FFFFu);
    }
}

// One block (1024 thr, 16 waves) per class, candidates register-resident.
// Per round: local max over K slots -> DPP wave max on score bits -> DPP wave
// min on idx among score-matching slots (exact (score desc, idx asc)) ->
// per-wave (score,~idx) u64 + box to LDS -> ONE barrier (double-buffered) ->
// redundant 16-way combine -> in-register suppression. No ds_bpermute chains,
// no global memory in the round loop.
__global__ __launch_bounds__(NMS_T) void nms_kernel(
    const float4* __restrict__ boxes, const uint2* __restrict__ cands,
    const int* __restrict__ counts, float* __restrict__ out)
{
    __shared__ unsigned long long pk[2][NMS_W];
    __shared__ float4             pb[2][NMS_W];

    int c = blockIdx.x;
    int tid = threadIdx.x;
    int lane = tid & 63;
    int wv = tid >> 6;

    int cnt = counts[c * CNT_STRIDE];
    if (cnt > CAP)  cnt = CAP;
    if (cnt > NCAP) cnt = NCAP;

    const uint2* cl = cands + (size_t)c * CAP;

    unsigned scu[NMS_K];   // score bits; 0 = dead slot
    unsigned ixu[NMS_K];
    float4 bx[NMS_K];
    float  ar[NMS_K];

#pragma unroll
    for (int k = 0; k < NMS_K; ++k) {
        int e = tid + k * NMS_T;
        scu[k] = 0u;
        ixu[k] = 0xFFFFFFFFu;
        bx[k] = make_float4(0.0f, 0.0f, 0.0f, 0.0f);
        ar[k] = 0.0f;
        if (e < cnt) {
            uint2 v = cl[e];
            scu[k] = v.x;
            ixu[k] = v.y;
            bx[k] = boxes[v.y];
            ar[k] = (bx[k].z - bx[k].x) * (bx[k].w - bx[k].y);
        }
    }

    float* ob  = out;             // 1600 boxes * 4
    float* os  = out + 6400;      // 1600 scores
    float* ocl = out + 8000;      // 1600 classes (as float)

    int r = 0;
    for (; r < MAXB; ++r) {
        // ---- wave argmax: max score (DPP), then min idx at that score ----
        unsigned lm = 0u;
#pragma unroll
        for (int k = 0; k < NMS_K; ++k) lm = lm > scu[k] ? lm : scu[k];
        unsigned smax = wave_max_bcast(lm);

        unsigned li = 0xFFFFFFFFu;
#pragma unroll
        for (int k = 0; k < NMS_K; ++k)
            if (scu[k] == smax && ixu[k] < li) li = ixu[k];
        unsigned bidx = wave_min_bcast(li);   // 0xFFFFFFFF if wave empty

        int p = r & 1;
        if (lane == 0)
            pk[p][wv] = ((unsigned long long)smax << 32) | (unsigned)(~bidx);
        if (smax != 0u) {
#pragma unroll
            for (int k = 0; k < NMS_K; ++k)
                if (scu[k] == smax && ixu[k] == bidx) pb[p][wv] = bx[k];
        }
        __syncthreads();   // single barrier/round (slots double-buffered)

        unsigned long long gb = pk[p][0];
        int gw = 0;
#pragma unroll
        for (int w = 1; w < NMS_W; ++w) {
            unsigned long long t = pk[p][w];
            if (t > gb) { gb = t; gw = w; }
        }

        float best_s = __uint_as_float((unsigned)(gb >> 32));
        if (best_s < 0.6f) break;   // uniform exit (gb==0 -> 0.0)

        float4 sb = pb[p][gw];      // LDS broadcast read
        unsigned best_i = ~(unsigned)gb;
        float area_s = (sb.z - sb.x) * (sb.w - sb.y);

        if (tid == 0) {
            int o = c * MAXB + r;
            ob[o * 4 + 0] = sb.x;
            ob[o * 4 + 1] = sb.y;
            ob[o * 4 + 2] = sb.z;
            ob[o * 4 + 3] = sb.w;
            os[o]  = best_s;
            ocl[o] = (float)c;
        }

        // ---- in-register suppression (reference IoU formula, exact) ----
#pragma unroll
        for (int k = 0; k < NMS_K; ++k) {
            if (scu[k] != 0u) {
                float y1 = fmaxf(sb.x, bx[k].x);
                float x1 = fmaxf(sb.y, bx[k].y);
                float y2 = fminf(sb.z, bx[k].z);
                float x2 = fminf(sb.w, bx[k].w);
                float ih = fmaxf(y2 - y1, 0.0f);
                float iw = fmaxf(x2 - x1, 0.0f);
                float inter = ih * iw;
                float un = area_s + ar[k] - inter;
                float iou = (un > 0.0f) ? (inter / un) : 0.0f;
                if (iou > 0.5f || ixu[k] == best_i) scu[k] = 0u;
            }
        }
    }

    // remaining (invalid) slots: zero boxes/scores, class = -1
    for (int q = r + tid; q < MAXB; q += NMS_T) {
        int o = c * MAXB + q;
        ob[o * 4 + 0] = 0.0f;
        ob[o * 4 + 1] = 0.0f;
        ob[o * 4 + 2] = 0.0f;
        ob[o * 4 + 3] = 0.0f;
        os[o]  = 0.0f;
        ocl[o] = -1.0f;
    }
}

extern "C" void kernel_launch(void* const* d_in, const int* in_sizes, int n_in,
                              void* d_out, int out_size, void* d_ws, size_t ws_size,
                              hipStream_t stream) {
    const float* feats0 = (const float*)d_in[0];
    const float* feats1 = (const float*)d_in[1];
    float* out = (float*)d_out;

    char* ws = (char*)d_ws;
    float4* boxes = (float4*)ws;                       // NTOT*16B = 2,211,840
    int*    counts = (int*)(ws + 2211840);             // 80*16*4B
    uint2*  cands  = (uint2*)(ws + 2211840 + 8192);    // 80*CAP*8B = 5.24MB

    init_counts<<<(NCLS * CNT_STRIDE + 255) / 256, 256, 0, stream>>>(counts);

    decode_kernel<<<N0 / 256, 256, 0, stream>>>(
        feats0, boxes, cands, counts, 96, 0,
        81.0f, 82.0f, 135.0f, 169.0f, 344.0f, 319.0f);
    decode_kernel<<<N1 / 256, 256, 0, stream>>>(
        feats1, boxes, cands, counts, 192, N0,
        23.0f, 27.0f, 37.0f, 58.0f, 81.0f, 82.0f);

    nms_kernel<<<NCLS, NMS_T, 0, stream>>>(boxes, cands, counts, out);
}

// Round 6
// 56.786 us; speedup vs baseline: 24.8240x; 1.9021x over previous
//
#include <hip/hip_runtime.h>

#define NCLS 80
#define MAXB 20
#define N0 27648     // 96*96*3
#define N1 110592    // 192*192*3
#define NTOT (N0 + N1)
#define CAP 8192       // per-class candidate capacity in workspace
#define STAGE 1536     // per-block candidate staging in decode
#define CNT_STRIDE 16  // pad class counters to one 64B line each
#define NMS_T 1024
#define NB 1664        // score histogram buckets (26*64); max bucket 1638
#define TARGET 128     // top-k cut for fast NMS path
#define SCAP 256       // compact-list capacity (4 slots/lane in wave 0)

__device__ __forceinline__ float sigf(float x) {
    return 1.0f / (1.0f + expf(-x));
}

// Wave64 reduce via DPP (row_shr 1/2/4/8 + row_bcast 15/31), broadcast from
// lane 63. Pure VALU. Proven exact in round 5 (absmax 0).
__device__ __forceinline__ unsigned wave_max_bcast(unsigned x) {
    unsigned t;
    t = (unsigned)__builtin_amdgcn_update_dpp((int)x, (int)x, 0x111, 0xF, 0xF, false); x = x > t ? x : t;
    t = (unsigned)__builtin_amdgcn_update_dpp((int)x, (int)x, 0x112, 0xF, 0xF, false); x = x > t ? x : t;
    t = (unsigned)__builtin_amdgcn_update_dpp((int)x, (int)x, 0x114, 0xF, 0xF, false); x = x > t ? x : t;
    t = (unsigned)__builtin_amdgcn_update_dpp((int)x, (int)x, 0x118, 0xF, 0xF, false); x = x > t ? x : t;
    t = (unsigned)__builtin_amdgcn_update_dpp((int)x, (int)x, 0x142, 0xF, 0xF, false); x = x > t ? x : t;
    t = (unsigned)__builtin_amdgcn_update_dpp((int)x, (int)x, 0x143, 0xF, 0xF, false); x = x > t ? x : t;
    return (unsigned)__builtin_amdgcn_readlane((int)x, 63);
}

__device__ __forceinline__ unsigned wave_min_bcast(unsigned x) {
    unsigned t;
    t = (unsigned)__builtin_amdgcn_update_dpp((int)x, (int)x, 0x111, 0xF, 0xF, false); x = x < t ? x : t;
    t = (unsigned)__builtin_amdgcn_update_dpp((int)x, (int)x, 0x112, 0xF, 0xF, false); x = x < t ? x : t;
    t = (unsigned)__builtin_amdgcn_update_dpp((int)x, (int)x, 0x114, 0xF, 0xF, false); x = x < t ? x : t;
    t = (unsigned)__builtin_amdgcn_update_dpp((int)x, (int)x, 0x118, 0xF, 0xF, false); x = x < t ? x : t;
    t = (unsigned)__builtin_amdgcn_update_dpp((int)x, (int)x, 0x142, 0xF, 0xF, false); x = x < t ? x : t;
    t = (unsigned)__builtin_amdgcn_update_dpp((int)x, (int)x, 0x143, 0xF, 0xF, false); x = x < t ? x : t;
    return (unsigned)__builtin_amdgcn_readlane((int)x, 63);
}

__global__ __launch_bounds__(256) void init_counts(int* counts) {
    int t = blockIdx.x * 256 + threadIdx.x;
    if (t < NCLS * CNT_STRIDE) counts[t] = 0;
}

// Both layers in one launch: blocks [0,108) -> layer0 (S=96), [108,540) ->
// layer1 (S=192). Phase 0: decode+conf-gate into LDS pass-list. Phase 1:
// dense (anchor,class) emission (full lanes, coalesced prob loads).
// Phases 2-4: per-class counts -> one reserve atomic per (block,class) ->
// scatter. Proven exact (rounds 2-5, absmax 0).
__global__ __launch_bounds__(256) void decode_kernel(
    const float* __restrict__ feats0, const float* __restrict__ feats1,
    float4* __restrict__ boxes, uint2* __restrict__ cands,
    int* __restrict__ counts)
{
    __shared__ unsigned p_gi[256];
    __shared__ float    p_conf[256];
    __shared__ int s_npass;
    __shared__ float    s_esc[STAGE];
    __shared__ unsigned s_ent[STAGE];   // gi | (class<<18)
    __shared__ int s_n;
    __shared__ int s_cnt[NCLS];
    __shared__ int s_base[NCLS];

    int tid = threadIdx.x;
    if (tid == 0) { s_npass = 0; s_n = 0; }
    for (int c = tid; c < NCLS; c += 256) s_cnt[c] = 0;
    __syncthreads();

    const float* feats;
    int S, base, i;
    float aw0, ah0, aw1, ah1, aw2, ah2;
    if (blockIdx.x < N0 / 256) {
        feats = feats0; S = 96; base = 0;
        i = blockIdx.x * 256 + tid;
        aw0 = 81.0f;  ah0 = 82.0f;  aw1 = 135.0f; ah1 = 169.0f; aw2 = 344.0f; ah2 = 319.0f;
    } else {
        feats = feats1; S = 192; base = N0;
        i = (blockIdx.x - N0 / 256) * 256 + tid;
        aw0 = 23.0f;  ah0 = 27.0f;  aw1 = 37.0f;  ah1 = 58.0f;  aw2 = 81.0f;  ah2 = 82.0f;
    }

    int a = i % 3;
    int cell = i / 3;
    int gx = cell % S;
    int gy = cell / S;

    const float* f = feats + (size_t)i * 85;
    float tx = f[0], ty = f[1], tw = f[2], th = f[3], tc = f[4];

    float Sf = (float)S;
    float inpf = Sf * 32.0f;
    float aw = (a == 0) ? aw0 : ((a == 1) ? aw1 : aw2);
    float ah = (a == 0) ? ah0 : ((a == 1) ? ah1 : ah2);

    // yolo_head
    float x = (sigf(tx) + (float)gx) / Sf;
    float y = (sigf(ty) + (float)gy) / Sf;
    float w = expf(tw) * aw / inpf;
    float h = expf(th) * ah / inpf;

    // yolo_correct_boxes: letterbox constants identical for both layers
    const float OFF = 0.21875f;
    const float SC  = 3072.0f / 1728.0f;
    float yy = (y - OFF) * SC;
    float hh = h * SC;

    float ymin = (yy - hh * 0.5f) * 1080.0f;
    float xmin = (x  - w  * 0.5f) * 1920.0f;
    float ymax = (yy + hh * 0.5f) * 1080.0f;
    float xmax = (x  + w  * 0.5f) * 1920.0f;

    int gi = base + i;
    boxes[gi] = make_float4(ymin, xmin, ymax, xmax);

    float sconf = sigf(tc);
    // sconf < 0.6 => sconf*sigmoid(p) < 0.6 for all classes (exact bound).
    if (sconf >= 0.6f) {
        int sl = atomicAdd(&s_npass, 1);   // <= 256
        p_gi[sl] = (unsigned)gi;
        p_conf[sl] = sconf;
    }
    __syncthreads();

    int tot = s_npass * NCLS;
    for (int wk = tid; wk < tot; wk += 256) {
        int sl = wk / NCLS;
        int c  = wk - sl * NCLS;
        float pv = feats[(size_t)(p_gi[sl] - (unsigned)base) * 85 + 5 + c];
        float s = p_conf[sl] * sigf(pv);
        if (s >= 0.6f) {
            int e = atomicAdd(&s_n, 1);
            if (e < STAGE) {
                s_esc[e] = s;
                s_ent[e] = p_gi[sl] | ((unsigned)c << 18);
            }
        }
    }
    __syncthreads();

    int n = s_n < STAGE ? s_n : STAGE;

    for (int e = tid; e < n; e += 256)
        atomicAdd(&s_cnt[s_ent[e] >> 18], 1);
    __syncthreads();

    for (int c = tid; c < NCLS; c += 256) {
        int k = s_cnt[c];
        s_base[c] = (k > 0) ? atomicAdd(&counts[c * CNT_STRIDE], k) : 0;
        s_cnt[c] = 0;
    }
    __syncthreads();

    for (int e = tid; e < n; e += 256) {
        unsigned ent = s_ent[e];
        int c = ent >> 18;
        int lpos = atomicAdd(&s_cnt[c], 1);
        int pos = s_base[c] + lpos;
        if (pos < CAP)
            cands[(size_t)c * CAP + pos] =
                make_uint2(__float_as_uint(s_esc[e]), ent & 0x3FFFFu);
    }
}

// One block per class.
// Phase 1 (16 waves): score-bits histogram -> exact TARGET-th threshold
// bucket -> compact all candidates >= bucket floor (+boxes) into LDS.
// Phase 2 (wave 0, barrier-free): register-resident greedy NMS over the
// compact list; DPP argmax, ballot+readlane box broadcast, 4-slot suppress.
// Greedy NMS only examines candidates ranked above the 20th kept, so the
// compact list is exact unless it exhausts with <20 kept while below-
// threshold candidates exist -> full-list fallback (exact, ~never taken).
__global__ __launch_bounds__(NMS_T) void nms_kernel(
    const float4* __restrict__ boxes, const uint2* __restrict__ cands,
    const int* __restrict__ counts, float* __restrict__ out)
{
    __shared__ int s_hist[NB];
    __shared__ int s_sup[NB / 64];
    __shared__ int s_tau;
    __shared__ int s_m;
    __shared__ float4   s_cbox[SCAP];
    __shared__ unsigned s_csc[SCAP];
    __shared__ unsigned s_cix[SCAP];
    __shared__ unsigned char s_alive[CAP];   // fallback only

    int c = blockIdx.x;
    int tid = threadIdx.x;

    int cnt = counts[c * CNT_STRIDE];
    if (cnt > CAP) cnt = CAP;

    const uint2* cl = cands + (size_t)c * CAP;

    // ---- phase 1: histogram on score bits (scores in [0.6, 1.0]) ----
    for (int b = tid; b < NB; b += NMS_T) s_hist[b] = 0;
    if (tid == 0) { s_tau = 0; s_m = 0; }
    __syncthreads();

    for (int e = tid; e < cnt; e += NMS_T) {
        unsigned sc = cl[e].x;                       // >= 0x3F19999A (0.6f)
        atomicAdd(&s_hist[(sc - 0x3F199999u) >> 12], 1);
    }
    __syncthreads();

    if (tid < NB / 64) {
        int acc = 0;
        for (int b = 0; b < 64; ++b) acc += s_hist[tid * 64 + b];
        s_sup[tid] = acc;
    }
    __syncthreads();

    if (tid == 0) {
        int acc = 0, tau = 0;
        for (int sb = NB / 64 - 1; sb >= 0; --sb) {
            if (acc + s_sup[sb] >= TARGET) {
                int a2 = acc;
                for (int b = 63; b >= 0; --b) {
                    a2 += s_hist[sb * 64 + b];
                    if (a2 >= TARGET) { tau = sb * 64 + b; break; }
                }
                break;
            }
            acc += s_sup[sb];
        }
        s_tau = tau;   // 0 if total < TARGET (take all)
    }
    __syncthreads();

    int tau = s_tau;
    for (int e = tid; e < cnt; e += NMS_T) {
        uint2 v = cl[e];
        if ((int)((v.x - 0x3F199999u) >> 12) >= tau) {
            int p = atomicAdd(&s_m, 1);
            if (p < SCAP) {
                s_csc[p] = v.x;
                s_cix[p] = v.y;
                s_cbox[p] = boxes[v.y];
            }
        }
    }
    __syncthreads();

    if (tid >= 64) return;          // only wave 0 continues (no more barriers)

    int lane = tid;
    int m = s_m;
    bool need_fb = (m > SCAP);
    if (m > SCAP) m = SCAP;

    float* ob  = out;             // 1600 boxes * 4
    float* os  = out + 6400;      // 1600 scores
    float* ocl = out + 8000;      // 1600 classes (as float)

    int sel = 0;

    if (!need_fb) {
        unsigned scu[4], ixu[4];
        float4 bx[4];
        float  ar[4];
#pragma unroll
        for (int k = 0; k < 4; ++k) {
            int e = lane + k * 64;
            scu[k] = 0u; ixu[k] = 0xFFFFFFFFu;
            bx[k] = make_float4(0.f, 0.f, 0.f, 0.f);
            ar[k] = 0.f;
            if (e < m) {
                scu[k] = s_csc[e];
                ixu[k] = s_cix[e];
                bx[k] = s_cbox[e];
                ar[k] = (bx[k].z - bx[k].x) * (bx[k].w - bx[k].y);
            }
        }

        for (; sel < MAXB; ++sel) {
            unsigned lm = 0u;
#pragma unroll
            for (int k = 0; k < 4; ++k) lm = lm > scu[k] ? lm : scu[k];
            unsigned smax = wave_max_bcast(lm);
            if (smax == 0u) {
                if (m < cnt) need_fb = true;   // compact list exhausted early
                break;
            }
            unsigned li = 0xFFFFFFFFu;
#pragma unroll
            for (int k = 0; k < 4; ++k)
                if (scu[k] == smax && ixu[k] < li) li = ixu[k];
            unsigned bidx = wave_min_bcast(li);

            bool has = false;
            float4 ob_ = make_float4(0.f, 0.f, 0.f, 0.f);
#pragma unroll
            for (int k = 0; k < 4; ++k)
                if (scu[k] == smax && ixu[k] == bidx) { ob_ = bx[k]; has = true; }
            unsigned long long mk = __ballot(has);
            int src = __ffsll((long long)mk) - 1;
            float4 sb;
            sb.x = __int_as_float(__builtin_amdgcn_readlane(__float_as_int(ob_.x), src));
            sb.y = __int_as_float(__builtin_amdgcn_readlane(__float_as_int(ob_.y), src));
            sb.z = __int_as_float(__builtin_amdgcn_readlane(__float_as_int(ob_.z), src));
            sb.w = __int_as_float(__builtin_amdgcn_readlane(__float_as_int(ob_.w), src));
            float area_s = (sb.z - sb.x) * (sb.w - sb.y);

            if (lane == 0) {
                int o = c * MAXB + sel;
                ob[o * 4 + 0] = sb.x; ob[o * 4 + 1] = sb.y;
                ob[o * 4 + 2] = sb.z; ob[o * 4 + 3] = sb.w;
                os[o]  = __uint_as_float(smax);
                ocl[o] = (float)c;
            }

#pragma unroll
            for (int k = 0; k < 4; ++k) {
                if (scu[k] != 0u) {
                    float y1 = fmaxf(sb.x, bx[k].x);
                    float x1 = fmaxf(sb.y, bx[k].y);
                    float y2 = fminf(sb.z, bx[k].z);
                    float x2 = fminf(sb.w, bx[k].w);
                    float inter = fmaxf(y2 - y1, 0.f) * fmaxf(x2 - x1, 0.f);
                    float un = area_s + ar[k] - inter;
                    float iou = (un > 0.f) ? (inter / un) : 0.f;
                    if (iou > 0.5f || ixu[k] == bidx) scu[k] = 0u;
                }
            }
        }
    }

    if (need_fb) {
        // exact full-list greedy NMS from scratch (statistically never taken)
        for (int e = lane; e < cnt; e += 64) s_alive[e] = 1;
        sel = 0;
        for (; sel < MAXB; ++sel) {
            unsigned bs = 0u, bi = 0xFFFFFFFFu;
            for (int e = lane; e < cnt; e += 64) {
                if (s_alive[e]) {
                    uint2 v = cl[e];
                    if (v.x > bs || (v.x == bs && v.y < bi)) { bs = v.x; bi = v.y; }
                }
            }
            unsigned smax = wave_max_bcast(bs);
            if (smax == 0u) break;
            unsigned li = (bs == smax) ? bi : 0xFFFFFFFFu;
            unsigned bidx = wave_min_bcast(li);

            float4 sb = boxes[bidx];
            float area_s = (sb.z - sb.x) * (sb.w - sb.y);

            if (lane == 0) {
                int o = c * MAXB + sel;
                ob[o * 4 + 0] = sb.x; ob[o * 4 + 1] = sb.y;
                ob[o * 4 + 2] = sb.z; ob[o * 4 + 3] = sb.w;
                os[o]  = __uint_as_float(smax);
                ocl[o] = (float)c;
            }

            for (int e = lane; e < cnt; e += 64) {
                if (s_alive[e]) {
                    uint2 v = cl[e];
                    float4 cb = boxes[v.y];
                    float y1 = fmaxf(sb.x, cb.x);
                    float x1 = fmaxf(sb.y, cb.y);
                    float y2 = fminf(sb.z, cb.z);
                    float x2 = fminf(sb.w, cb.w);
                    float inter = fmaxf(y2 - y1, 0.f) * fmaxf(x2 - x1, 0.f);
                    float area_c = (cb.z - cb.x) * (cb.w - cb.y);
                    float un = area_s + area_c - inter;
                    float iou = (un > 0.f) ? (inter / un) : 0.f;
                    if (iou > 0.5f || v.y == bidx) s_alive[e] = 0;
                }
            }
        }
    }

    // invalid slots: zero boxes/scores, class = -1 (lane-parallel)
    for (int q = sel + lane; q < MAXB; q += 64) {
        int o = c * MAXB + q;
        ob[o * 4 + 0] = 0.0f; ob[o * 4 + 1] = 0.0f;
        ob[o * 4 + 2] = 0.0f; ob[o * 4 + 3] = 0.0f;
        os[o]  = 0.0f;
        ocl[o] = -1.0f;
    }
}

extern "C" void kernel_launch(void* const* d_in, const int* in_sizes, int n_in,
                              void* d_out, int out_size, void* d_ws, size_t ws_size,
                              hipStream_t stream) {
    const float* feats0 = (const float*)d_in[0];
    const float* feats1 = (const float*)d_in[1];
    float* out = (float*)d_out;

    char* ws = (char*)d_ws;
    float4* boxes = (float4*)ws;                       // NTOT*16B = 2,211,840
    int*    counts = (int*)(ws + 2211840);             // 80*16*4B
    uint2*  cands  = (uint2*)(ws + 2211840 + 8192);    // 80*CAP*8B = 5.24MB

    init_counts<<<(NCLS * CNT_STRIDE + 255) / 256, 256, 0, stream>>>(counts);

    decode_kernel<<<NTOT / 256, 256, 0, stream>>>(feats0, feats1, boxes, cands, counts);

    nms_kernel<<<NCLS, NMS_T, 0, stream>>>(boxes, cands, counts, out);
}

// Round 7
// 51.539 us; speedup vs baseline: 27.3513x; 1.1018x over previous
//
#include <hip/hip_runtime.h>

#define NCLS 80
#define MAXB 20
#define N0 27648     // 96*96*3
#define N1 110592    // 192*192*3
#define NTOT (N0 + N1)
#define CAP 8192       // per-class candidate capacity in workspace
#define DT 512         // decode block size
#define DSTAGE 3072    // per-block candidate staging (expected ~1120, +30 sigma)
#define CNT_STRIDE 16  // pad class counters to one 64B line each
#define NMS_T 1024
#define NB 256         // score histogram buckets ((bits-0.6f)>>15, max 204)
#define TARGET 128     // top-k cut for fast NMS path
#define SCAP 256       // compact-list capacity (4 slots/lane in wave 0)

__device__ __forceinline__ float sigf(float x) {
    return 1.0f / (1.0f + expf(-x));
}

// ---- DPP wave64 primitives (proven exact in rounds 5-6, absmax 0) ----
__device__ __forceinline__ unsigned wave_max_bcast(unsigned x) {
    unsigned t;
    t = (unsigned)__builtin_amdgcn_update_dpp((int)x, (int)x, 0x111, 0xF, 0xF, false); x = x > t ? x : t;
    t = (unsigned)__builtin_amdgcn_update_dpp((int)x, (int)x, 0x112, 0xF, 0xF, false); x = x > t ? x : t;
    t = (unsigned)__builtin_amdgcn_update_dpp((int)x, (int)x, 0x114, 0xF, 0xF, false); x = x > t ? x : t;
    t = (unsigned)__builtin_amdgcn_update_dpp((int)x, (int)x, 0x118, 0xF, 0xF, false); x = x > t ? x : t;
    t = (unsigned)__builtin_amdgcn_update_dpp((int)x, (int)x, 0x142, 0xF, 0xF, false); x = x > t ? x : t;
    t = (unsigned)__builtin_amdgcn_update_dpp((int)x, (int)x, 0x143, 0xF, 0xF, false); x = x > t ? x : t;
    return (unsigned)__builtin_amdgcn_readlane((int)x, 63);
}

__device__ __forceinline__ unsigned wave_min_bcast(unsigned x) {
    unsigned t;
    t = (unsigned)__builtin_amdgcn_update_dpp((int)x, (int)x, 0x111, 0xF, 0xF, false); x = x < t ? x : t;
    t = (unsigned)__builtin_amdgcn_update_dpp((int)x, (int)x, 0x112, 0xF, 0xF, false); x = x < t ? x : t;
    t = (unsigned)__builtin_amdgcn_update_dpp((int)x, (int)x, 0x114, 0xF, 0xF, false); x = x < t ? x : t;
    t = (unsigned)__builtin_amdgcn_update_dpp((int)x, (int)x, 0x118, 0xF, 0xF, false); x = x < t ? x : t;
    t = (unsigned)__builtin_amdgcn_update_dpp((int)x, (int)x, 0x142, 0xF, 0xF, false); x = x < t ? x : t;
    t = (unsigned)__builtin_amdgcn_update_dpp((int)x, (int)x, 0x143, 0xF, 0xF, false); x = x < t ? x : t;
    return (unsigned)__builtin_amdgcn_readlane((int)x, 63);
}

// Wave64 inclusive +scan (LLVM AtomicOptimizer idiom: row_shr 1/2/4/8 with
// old=0 on invalid sources, then masked row_bcast15 (rows 1,3) and
// row_bcast31 (rows 2,3)).
__device__ __forceinline__ unsigned wave_incl_scan(unsigned x) {
    x += (unsigned)__builtin_amdgcn_update_dpp(0, (int)x, 0x111, 0xF, 0xF, false);
    x += (unsigned)__builtin_amdgcn_update_dpp(0, (int)x, 0x112, 0xF, 0xF, false);
    x += (unsigned)__builtin_amdgcn_update_dpp(0, (int)x, 0x114, 0xF, 0xF, false);
    x += (unsigned)__builtin_amdgcn_update_dpp(0, (int)x, 0x118, 0xF, 0xF, false);
    x += (unsigned)__builtin_amdgcn_update_dpp(0, (int)x, 0x142, 0xA, 0xF, false);
    x += (unsigned)__builtin_amdgcn_update_dpp(0, (int)x, 0x143, 0xC, 0xF, false);
    return x;
}

// Both layers in one launch: blocks [0,54) -> layer0 (S=96), [54,270) ->
// layer1 (S=192). Phase 0: conf-gate only (1 scalar load / anchor).
// Phase 0b: box decode+write for PASS anchors only (dense over pass-list).
// Phase 1: dense (anchor,class) score emission. Phases 2-4: per-class count
// -> one reserve atomic per (block,class) -> scatter. 512-thread blocks
// halve the reserve-atomic per-line serialization vs 256.
__global__ __launch_bounds__(DT) void decode_kernel(
    const float* __restrict__ feats0, const float* __restrict__ feats1,
    float4* __restrict__ boxes, uint2* __restrict__ cands,
    int* __restrict__ counts)
{
    __shared__ unsigned p_gi[DT];
    __shared__ float    p_conf[DT];
    __shared__ int s_npass;
    __shared__ float    s_esc[DSTAGE];
    __shared__ unsigned s_ent[DSTAGE];   // gi | (class<<18)
    __shared__ int s_n;
    __shared__ int s_cnt[NCLS];
    __shared__ int s_base[NCLS];

    int tid = threadIdx.x;
    if (tid == 0) { s_npass = 0; s_n = 0; }
    for (int c = tid; c < NCLS; c += DT) s_cnt[c] = 0;
    __syncthreads();

    const float* feats;
    int S, base, i;
    float aw0, ah0, aw1, ah1, aw2, ah2;
    if (blockIdx.x < N0 / DT) {
        feats = feats0; S = 96; base = 0;
        i = blockIdx.x * DT + tid;
        aw0 = 81.0f;  ah0 = 82.0f;  aw1 = 135.0f; ah1 = 169.0f; aw2 = 344.0f; ah2 = 319.0f;
    } else {
        feats = feats1; S = 192; base = N0;
        i = (blockIdx.x - N0 / DT) * DT + tid;
        aw0 = 23.0f;  ah0 = 27.0f;  aw1 = 37.0f;  ah1 = 58.0f;  aw2 = 81.0f;  ah2 = 82.0f;
    }

    // ---- phase 0: conf gate (only f[4] needed) ----
    float sconf = sigf(feats[(size_t)i * 85 + 4]);
    if (sconf >= 0.6f) {   // sconf < 0.6 => all class scores < 0.6 (exact)
        int sl = atomicAdd(&s_npass, 1);   // <= DT
        p_gi[sl] = (unsigned)(base + i);
        p_conf[sl] = sconf;
    }
    __syncthreads();

    int npass = s_npass;

    // ---- phase 0b: box decode + write for pass anchors only ----
    for (int e = tid; e < npass; e += DT) {
        int il = (int)p_gi[e] - base;
        int a = il % 3;
        int cell = il / 3;
        int gx = cell % S;
        int gy = cell / S;
        const float* f = feats + (size_t)il * 85;
        float tx = f[0], ty = f[1], tw = f[2], th = f[3];

        float Sf = (float)S;
        float inpf = Sf * 32.0f;
        float aw = (a == 0) ? aw0 : ((a == 1) ? aw1 : aw2);
        float ah = (a == 0) ? ah0 : ((a == 1) ? ah1 : ah2);

        float x = (sigf(tx) + (float)gx) / Sf;
        float y = (sigf(ty) + (float)gy) / Sf;
        float w = expf(tw) * aw / inpf;
        float h = expf(th) * ah / inpf;

        // yolo_correct_boxes: letterbox constants identical for both layers
        const float OFF = 0.21875f;
        const float SC  = 3072.0f / 1728.0f;
        float yy = (y - OFF) * SC;
        float hh = h * SC;

        boxes[p_gi[e]] = make_float4((yy - hh * 0.5f) * 1080.0f,
                                     (x  - w  * 0.5f) * 1920.0f,
                                     (yy + hh * 0.5f) * 1080.0f,
                                     (x  + w  * 0.5f) * 1920.0f);
    }

    // ---- phase 1: dense (pass-anchor, class) score emission ----
    int tot = npass * NCLS;
    for (int wk = tid; wk < tot; wk += DT) {
        int sl = wk / NCLS;
        int c  = wk - sl * NCLS;
        float pv = feats[(size_t)(p_gi[sl] - (unsigned)base) * 85 + 5 + c];
        float s = p_conf[sl] * sigf(pv);
        if (s >= 0.6f) {
            int e = atomicAdd(&s_n, 1);
            if (e < DSTAGE) {
                s_esc[e] = s;
                s_ent[e] = p_gi[sl] | ((unsigned)c << 18);
            }
        }
    }
    __syncthreads();

    int n = s_n < DSTAGE ? s_n : DSTAGE;

    // ---- phase 2: per-class block totals ----
    for (int e = tid; e < n; e += DT)
        atomicAdd(&s_cnt[s_ent[e] >> 18], 1);
    __syncthreads();

    // ---- phase 3: one reserve atomic per (block,class), padded lines ----
    for (int c = tid; c < NCLS; c += DT) {
        int k = s_cnt[c];
        s_base[c] = (k > 0) ? atomicAdd(&counts[c * CNT_STRIDE], k) : 0;
        s_cnt[c] = 0;
    }
    __syncthreads();

    // ---- phase 4: scatter into reserved slices ----
    for (int e = tid; e < n; e += DT) {
        unsigned ent = s_ent[e];
        int c = ent >> 18;
        int lpos = atomicAdd(&s_cnt[c], 1);
        int pos = s_base[c] + lpos;
        if (pos < CAP)
            cands[(size_t)c * CAP + pos] =
                make_uint2(__float_as_uint(s_esc[e]), ent & 0x3FFFFu);
    }
}

// One block per class.
// Phase 1 (16 waves): 256-bucket score histogram -> wave-0 DPP-scan finds the
// exact TARGET-th threshold bucket -> compact all cands >= bucket floor.
// Phase 2 (wave 0, barrier-free): register-resident greedy NMS (DPP argmax,
// ballot+readlane box broadcast, 4-slot suppression). Compact list is exact
// unless it exhausts with <MAXB kept while below-cut candidates exist, or
// overflows SCAP -> exact full-list fallback.
__global__ __launch_bounds__(NMS_T) void nms_kernel(
    const float4* __restrict__ boxes, const uint2* __restrict__ cands,
    const int* __restrict__ counts, float* __restrict__ out)
{
    __shared__ int s_hist[NB];
    __shared__ int s_tau;
    __shared__ int s_m;
    __shared__ float4   s_cbox[SCAP];
    __shared__ unsigned s_csc[SCAP];
    __shared__ unsigned s_cix[SCAP];
    __shared__ unsigned char s_alive[CAP];   // fallback only

    int c = blockIdx.x;
    int tid = threadIdx.x;

    int cnt = counts[c * CNT_STRIDE];
    if (cnt > CAP) cnt = CAP;

    const uint2* cl = cands + (size_t)c * CAP;

    // ---- phase 1: histogram on score bits (scores in [0.6, 1.0]) ----
    if (tid < NB) s_hist[tid] = 0;
    if (tid == 0) s_m = 0;
    __syncthreads();

    for (int e = tid; e < cnt; e += NMS_T) {
        unsigned sc = cl[e].x;                       // >= 0x3F19999A (0.6f)
        atomicAdd(&s_hist[(sc - 0x3F199999u) >> 15], 1);
    }
    __syncthreads();

    if (tid < 64) {
        // wave 0: find tau = max bucket with cum-from-top >= TARGET (exact)
        unsigned acc = 0;
        bool found = false;
        for (int ch = NB / 64 - 1; ch >= 0 && !found; --ch) {
            unsigned h = (unsigned)s_hist[ch * 64 + tid];
            unsigned incl = wave_incl_scan(h);
            unsigned total = (unsigned)__builtin_amdgcn_readlane((int)incl, 63);
            bool ok = acc + (total - incl + h) >= (unsigned)TARGET;
            unsigned long long mk = __ballot(ok);
            if (mk) {
                if (tid == 0) s_tau = ch * 64 + (63 - __builtin_clzll(mk));
                found = true;
            }
            acc += total;
        }
        if (!found && tid == 0) s_tau = 0;   // take all (total < TARGET)
    }
    __syncthreads();

    int tau = s_tau;
    for (int e = tid; e < cnt; e += NMS_T) {
        uint2 v = cl[e];
        if ((int)((v.x - 0x3F199999u) >> 15) >= tau) {
            int p = atomicAdd(&s_m, 1);
            if (p < SCAP) {
                s_csc[p] = v.x;
                s_cix[p] = v.y;
                s_cbox[p] = boxes[v.y];
            }
        }
    }
    __syncthreads();

    if (tid >= 64) return;          // only wave 0 continues (no more barriers)

    int lane = tid;
    int m = s_m;
    bool need_fb = (m > SCAP);
    if (m > SCAP) m = SCAP;

    float* ob  = out;             // 1600 boxes * 4
    float* os  = out + 6400;      // 1600 scores
    float* ocl = out + 8000;      // 1600 classes (as float)

    int sel = 0;

    if (!need_fb) {
        unsigned scu[4], ixu[4];
        float4 bx[4];
        float  ar[4];
#pragma unroll
        for (int k = 0; k < 4; ++k) {
            int e = lane + k * 64;
            scu[k] = 0u; ixu[k] = 0xFFFFFFFFu;
            bx[k] = make_float4(0.f, 0.f, 0.f, 0.f);
            ar[k] = 0.f;
            if (e < m) {
                scu[k] = s_csc[e];
                ixu[k] = s_cix[e];
                bx[k] = s_cbox[e];
                ar[k] = (bx[k].z - bx[k].x) * (bx[k].w - bx[k].y);
            }
        }

        for (; sel < MAXB; ++sel) {
            unsigned lm = 0u;
#pragma unroll
            for (int k = 0; k < 4; ++k) lm = lm > scu[k] ? lm : scu[k];
            unsigned smax = wave_max_bcast(lm);
            if (smax == 0u) {
                if (m < cnt) need_fb = true;   // compact list exhausted early
                break;
            }
            unsigned li = 0xFFFFFFFFu;
#pragma unroll
            for (int k = 0; k < 4; ++k)
                if (scu[k] == smax && ixu[k] < li) li = ixu[k];
            unsigned bidx = wave_min_bcast(li);

            bool has = false;
            float4 ob_ = make_float4(0.f, 0.f, 0.f, 0.f);
#pragma unroll
            for (int k = 0; k < 4; ++k)
                if (scu[k] == smax && ixu[k] == bidx) { ob_ = bx[k]; has = true; }
            unsigned long long mk = __ballot(has);
            int src = __ffsll((long long)mk) - 1;
            float4 sb;
            sb.x = __int_as_float(__builtin_amdgcn_readlane(__float_as_int(ob_.x), src));
            sb.y = __int_as_float(__builtin_amdgcn_readlane(__float_as_int(ob_.y), src));
            sb.z = __int_as_float(__builtin_amdgcn_readlane(__float_as_int(ob_.z), src));
            sb.w = __int_as_float(__builtin_amdgcn_readlane(__float_as_int(ob_.w), src));
            float area_s = (sb.z - sb.x) * (sb.w - sb.y);

            if (lane == 0) {
                int o = c * MAXB + sel;
                ob[o * 4 + 0] = sb.x; ob[o * 4 + 1] = sb.y;
                ob[o * 4 + 2] = sb.z; ob[o * 4 + 3] = sb.w;
                os[o]  = __uint_as_float(smax);
                ocl[o] = (float)c;
            }

#pragma unroll
            for (int k = 0; k < 4; ++k) {
                if (scu[k] != 0u) {
                    float y1 = fmaxf(sb.x, bx[k].x);
                    float x1 = fmaxf(sb.y, bx[k].y);
                    float y2 = fminf(sb.z, bx[k].z);
                    float x2 = fminf(sb.w, bx[k].w);
                    float inter = fmaxf(y2 - y1, 0.f) * fmaxf(x2 - x1, 0.f);
                    float un = area_s + ar[k] - inter;
                    float iou = (un > 0.f) ? (inter / un) : 0.f;
                    if (iou > 0.5f || ixu[k] == bidx) scu[k] = 0u;
                }
            }
        }
    }

    if (need_fb) {
        // exact full-list greedy NMS from scratch (statistically never taken)
        for (int e = lane; e < cnt; e += 64) s_alive[e] = 1;
        sel = 0;
        for (; sel < MAXB; ++sel) {
            unsigned bs = 0u, bi = 0xFFFFFFFFu;
            for (int e = lane; e < cnt; e += 64) {
                if (s_alive[e]) {
                    uint2 v = cl[e];
                    if (v.x > bs || (v.x == bs && v.y < bi)) { bs = v.x; bi = v.y; }
                }
            }
            unsigned smax = wave_max_bcast(bs);
            if (smax == 0u) break;
            unsigned li = (bs == smax) ? bi : 0xFFFFFFFFu;
            unsigned bidx = wave_min_bcast(li);

            float4 sb = boxes[bidx];
            float area_s = (sb.z - sb.x) * (sb.w - sb.y);

            if (lane == 0) {
                int o = c * MAXB + sel;
                ob[o * 4 + 0] = sb.x; ob[o * 4 + 1] = sb.y;
                ob[o * 4 + 2] = sb.z; ob[o * 4 + 3] = sb.w;
                os[o]  = __uint_as_float(smax);
                ocl[o] = (float)c;
            }

            for (int e = lane; e < cnt; e += 64) {
                if (s_alive[e]) {
                    uint2 v = cl[e];
                    float4 cb = boxes[v.y];
                    float y1 = fmaxf(sb.x, cb.x);
                    float x1 = fmaxf(sb.y, cb.y);
                    float y2 = fminf(sb.z, cb.z);
                    float x2 = fminf(sb.w, cb.w);
                    float inter = fmaxf(y2 - y1, 0.f) * fmaxf(x2 - x1, 0.f);
                    float area_c = (cb.z - cb.x) * (cb.w - cb.y);
                    float un = area_s + area_c - inter;
                    float iou = (un > 0.f) ? (inter / un) : 0.f;
                    if (iou > 0.5f || v.y == bidx) s_alive[e] = 0;
                }
            }
        }
    }

    // invalid slots: zero boxes/scores, class = -1 (lane-parallel)
    for (int q = sel + lane; q < MAXB; q += 64) {
        int o = c * MAXB + q;
        ob[o * 4 + 0] = 0.0f; ob[o * 4 + 1] = 0.0f;
        ob[o * 4 + 2] = 0.0f; ob[o * 4 + 3] = 0.0f;
        os[o]  = 0.0f;
        ocl[o] = -1.0f;
    }
}

extern "C" void kernel_launch(void* const* d_in, const int* in_sizes, int n_in,
                              void* d_out, int out_size, void* d_ws, size_t ws_size,
                              hipStream_t stream) {
    const float* feats0 = (const float*)d_in[0];
    const float* feats1 = (const float*)d_in[1];
    float* out = (float*)d_out;

    char* ws = (char*)d_ws;
    float4* boxes = (float4*)ws;                       // NTOT*16B = 2,211,840
    int*    counts = (int*)(ws + 2211840);             // 80*16*4B
    uint2*  cands  = (uint2*)(ws + 2211840 + 8192);    // 80*CAP*8B = 5.24MB

    hipMemsetAsync(counts, 0, NCLS * CNT_STRIDE * sizeof(int), stream);

    decode_kernel<<<NTOT / DT, DT, 0, stream>>>(feats0, feats1, boxes, cands, counts);

    nms_kernel<<<NCLS, NMS_T, 0, stream>>>(boxes, cands, counts, out);
}